// Round 7
// baseline (918.861 us; speedup 1.0000x reference)
//
#include <hip/hip_runtime.h>

typedef __attribute__((ext_vector_type(4))) float f32x4;
typedef __attribute__((ext_vector_type(8))) short bf16x8;
typedef __attribute__((ext_vector_type(4))) short s16x4;

__device__ __forceinline__ short f2bf(float f) {
  union { float f; unsigned u; } x; x.f = f;
  return (short)((x.u + 0x7fffu + ((x.u >> 16) & 1u)) >> 16);   // RNE
}

__device__ __forceinline__ bf16x8 pack8(float4 a, float4 b) {
  bf16x8 v;
  v[0] = f2bf(a.x); v[1] = f2bf(a.y); v[2] = f2bf(a.z); v[3] = f2bf(a.w);
  v[4] = f2bf(b.x); v[5] = f2bf(b.y); v[6] = f2bf(b.z); v[7] = f2bf(b.w);
  return v;
}

// ---------------- prep: weights->bf16, q padded->bf16, bias [8][64][64] -----
__global__ __launch_bounds__(256) void prep_kernel(
    const float* __restrict__ qkv_w, const float* __restrict__ proj_w,
    const float* __restrict__ qg, const float* __restrict__ table,
    short* __restrict__ wq_b, short* __restrict__ wp_b,
    short* __restrict__ q_b, float* __restrict__ biasg)
{
  int idx = blockIdx.x * 256 + threadIdx.x;
  if (idx < 131072) { wq_b[idx] = f2bf(qkv_w[idx]); return; }
  idx -= 131072;
  if (idx < 65536) { wp_b[idx] = f2bf(proj_w[idx]); return; }
  idx -= 65536;
  if (idx < 1048576) {                       // q padded: [64 win][8 h][64 n][32 d]
    int d = idx & 31, n = (idx >> 5) & 63, hh = (idx >> 11) & 7, w = idx >> 14;
    float v = (n < 49) ? qg[((w * 8 + hh) * 49 + n) * 32 + d] : 0.f;
    q_b[idx] = f2bf(v);
    return;
  }
  idx -= 1048576;
  if (idx < 32768) {                         // bias padded: [8 h][64 q][64 k]
    int hh = idx >> 12, rem = idx & 4095;
    int q = rem >> 6, k = rem & 63;
    float v = 0.f;
    if (q < 49 && k < 49) {
      int di = q / 7 - k / 7 + 6, dj = q % 7 - k % 7 + 6;
      v = table[(di * 13 + dj) * 8 + hh];
    }
    biasg[idx] = v;
  }
}

// ---------------- K1: per-window kv GEMM -> global K / V^T ------------------
// block = 1 window, 512 thr = 8 waves, wave = 64-col strip.
// waves 0-3 (K, swapped mfma): write Kg[win][64 key][256 c] b64 rows.
// waves 4-7 (V, normal mfma):  write vTg[win][256 d][64 key] b64 rows.
// Pad rows (49-63) staged as zero -> kv pad = bias (finite), masked in K2.
__global__ __launch_bounds__(512, 4) void kv_win(
    const float* __restrict__ x, const short* __restrict__ wq_b,
    const float* __restrict__ qkv_b,
    short* __restrict__ Kg, short* __restrict__ vTg)
{
  __shared__ __align__(16) short As[64 * 256];        // 32 KiB
  const int tid = threadIdx.x, b = blockIdx.x;
  const int lane = tid & 63, w = tid >> 6;
  const int lr = lane & 15, lg = lane >> 4;

  const float* xsrc = x + (long)b * 49 * 256;
  #pragma unroll
  for (int it = 0; it < 4; ++it) {
    int slot = it * 512 + tid;
    int row = slot >> 5, s = slot & 31;
    bf16x8 v;
    if (row < 49) {
      const float4* p = (const float4*)(xsrc + row * 256 + s * 8);
      v = pack8(p[0], p[1]);
    } else {
      #pragma unroll
      for (int j = 0; j < 8; ++j) v[j] = 0;
    }
    *(bf16x8*)(&As[row * 256 + ((s ^ (row & 7)) << 3)]) = v;
  }
  __syncthreads();

  const bool isK = (w < 4);
  f32x4 acc[4][4] = {};
  const short* wbase = wq_b + (isK ? (w * 64) : (256 + (w - 4) * 64)) * 256;
  #pragma unroll 2
  for (int kk = 0; kk < 8; ++kk) {
    bf16x8 xa[4], wf[4];
    #pragma unroll
    for (int t = 0; t < 4; ++t) {
      int row = t * 16 + lr;
      xa[t] = *(const bf16x8*)(&As[row * 256 + (((kk * 4 + lg) ^ (row & 7)) << 3)]);
    }
    #pragma unroll
    for (int s = 0; s < 4; ++s)
      wf[s] = *(const bf16x8*)(wbase + (s * 16 + lr) * 256 + kk * 32 + lg * 8);
    __builtin_amdgcn_s_setprio(1);
    if (isK) {
      #pragma unroll
      for (int s = 0; s < 4; ++s)
        #pragma unroll
        for (int t = 0; t < 4; ++t)
          acc[s][t] = __builtin_amdgcn_mfma_f32_16x16x32_bf16(wf[s], xa[t], acc[s][t], 0, 0, 0);
    } else {
      #pragma unroll
      for (int t = 0; t < 4; ++t)
        #pragma unroll
        for (int s = 0; s < 4; ++s)
          acc[t][s] = __builtin_amdgcn_mfma_f32_16x16x32_bf16(xa[t], wf[s], acc[t][s], 0, 0, 0);
    }
    __builtin_amdgcn_s_setprio(0);
  }

  if (isK) {         // lane: c = w*64 + s*16 + lg*4 (+r), key = t*16 + lr
    #pragma unroll
    for (int s = 0; s < 4; ++s) {
      int c0 = w * 64 + s * 16 + lg * 4;
      float4 bv = *(const float4*)(qkv_b + c0);
      #pragma unroll
      for (int t = 0; t < 4; ++t) {
        int key = t * 16 + lr;
        s16x4 sv;
        sv[0] = f2bf(acc[s][t][0] + bv.x);
        sv[1] = f2bf(acc[s][t][1] + bv.y);
        sv[2] = f2bf(acc[s][t][2] + bv.z);
        sv[3] = f2bf(acc[s][t][3] + bv.w);
        *(s16x4*)(Kg + ((long)b * 64 + key) * 256 + c0) = sv;
      }
    }
  } else {           // lane: key = t*16 + lg*4 (+r), d = (w-4)*64 + s*16 + lr
    #pragma unroll
    for (int s = 0; s < 4; ++s) {
      int d = (w - 4) * 64 + s * 16 + lr;
      float bv = qkv_b[256 + d];
      #pragma unroll
      for (int t = 0; t < 4; ++t) {
        int key0 = t * 16 + lg * 4;
        s16x4 sv;
        sv[0] = f2bf(acc[t][s][0] + bv);
        sv[1] = f2bf(acc[t][s][1] + bv);
        sv[2] = f2bf(acc[t][s][2] + bv);
        sv[3] = f2bf(acc[t][s][3] + bv);
        *(s16x4*)(vTg + ((long)b * 256 + d) * 64 + key0) = sv;
      }
    }
  }
}

// ---------------- K2: attention + proj, K/V direct from global --------------
// block = 1 window, 1024 thr = 16 waves, wave = (head h, q-half qh).
// ONE barrier. K/V fragment loads are coalesced b128 thanks to K1's layouts.
__global__ __launch_bounds__(1024, 4) void attn_win(
    const short* __restrict__ Kg, const short* __restrict__ vTg,
    const short* __restrict__ q_b, const short* __restrict__ wp_b,
    const float* __restrict__ proj_b, const float* __restrict__ biasg,
    float* __restrict__ out)
{
  __shared__ __align__(16) char smem[65536];
  short* Ol = (short*)smem;                           // [64 q][256 c]
  const int tid = threadIdx.x, b = blockIdx.x;
  const int lane = tid & 63, w = tid >> 6;            // 0..15
  const int lr = lane & 15, lg = lane >> 4;
  short* Pw = (short*)(smem + 32768 + w * 2048);      // per-wave [32 q][32 k]

  const int h = w >> 1, qh = w & 1;

  // -- S^T = mfma(K, Q): st[kt][qt], lane holds S[q=qt*16+lr][key=kt*16+lg*4+r]
  f32x4 st[4][2] = {};
  {
    const short* qsrc = q_b + ((long)(b >> 6) * 8 + h) * 2048 + qh * 1024;
    bf16x8 qa[2], kb[4];
    #pragma unroll
    for (int qt = 0; qt < 2; ++qt)
      qa[qt] = *(const bf16x8*)(qsrc + (qt * 16 + lr) * 32 + lg * 8);
    #pragma unroll
    for (int kt = 0; kt < 4; ++kt)
      kb[kt] = *(const bf16x8*)(Kg + ((long)b * 64 + kt * 16 + lr) * 256 + h * 32 + lg * 8);
    __builtin_amdgcn_s_setprio(1);
    #pragma unroll
    for (int kt = 0; kt < 4; ++kt)
      #pragma unroll
      for (int qt = 0; qt < 2; ++qt)
        st[kt][qt] = __builtin_amdgcn_mfma_f32_16x16x32_bf16(kb[kt], qa[qt], st[kt][qt], 0, 0, 0);
    __builtin_amdgcn_s_setprio(0);
  }

  // -- softmax; row q = qh*32+qt*16+lr, keys in-lane (2 shfls per reduce) ---
  {
    const float* bh = biasg + h * 4096;
    const float sc = 0.17677669529663687f;            // 32^-0.5
    #pragma unroll
    for (int qt = 0; qt < 2; ++qt) {
      int q = qh * 32 + qt * 16 + lr;
      float mx = -1e30f;
      #pragma unroll
      for (int kt = 0; kt < 4; ++kt) {
        int key0 = kt * 16 + lg * 4;
        float4 bv = *(const float4*)(bh + q * 64 + key0);
        #pragma unroll
        for (int r = 0; r < 4; ++r) {
          float t = st[kt][qt][r] * sc + ((r == 0) ? bv.x : (r == 1) ? bv.y : (r == 2) ? bv.z : bv.w);
          if (key0 + r >= 49) t = -1e30f;
          st[kt][qt][r] = t;
          mx = fmaxf(mx, t);
        }
      }
      mx = fmaxf(mx, __shfl_xor(mx, 16));
      mx = fmaxf(mx, __shfl_xor(mx, 32));
      float sum = 0.f;
      #pragma unroll
      for (int kt = 0; kt < 4; ++kt)
        #pragma unroll
        for (int r = 0; r < 4; ++r) {
          float e = __expf(st[kt][qt][r] - mx);
          st[kt][qt][r] = e; sum += e;
        }
      sum += __shfl_xor(sum, 16);
      sum += __shfl_xor(sum, 32);
      float rinv = 1.f / sum;                         // fold 1/sum into P
      #pragma unroll
      for (int kt = 0; kt < 4; ++kt)
        #pragma unroll
        for (int r = 0; r < 4; ++r) st[kt][qt][r] *= rinv;
    }
  }

  // -- PV: O^T = mfma(V^T, P^T); P bounced through private per-wave LDS -----
  f32x4 o[2][2] = {};
  #pragma unroll
  for (int ks = 0; ks < 2; ++ks) {
    #pragma unroll
    for (int kh = 0; kh < 2; ++kh) {
      int kt = ks * 2 + kh;
      int kloc0 = kh * 16 + lg * 4;
      #pragma unroll
      for (int qt = 0; qt < 2; ++qt) {
        int qloc = qt * 16 + lr;
        s16x4 sv;
        sv[0] = f2bf(st[kt][qt][0]);
        sv[1] = f2bf(st[kt][qt][1]);
        sv[2] = f2bf(st[kt][qt][2]);
        sv[3] = f2bf(st[kt][qt][3]);
        *(s16x4*)(&Pw[qloc * 32 + ((((kloc0 >> 3) ^ ((qloc >> 1) & 3)) << 3)) + (kloc0 & 7)]) = sv;
      }
    }
    bf16x8 pa[2], vb[2];
    #pragma unroll
    for (int qt = 0; qt < 2; ++qt) {
      int qloc = qt * 16 + lr;
      pa[qt] = *(const bf16x8*)(&Pw[qloc * 32 + ((lg ^ ((qloc >> 1) & 3)) << 3)]);
    }
    #pragma unroll
    for (int dt = 0; dt < 2; ++dt)
      vb[dt] = *(const bf16x8*)(vTg + ((long)b * 256 + h * 32 + dt * 16 + lr) * 64 + ks * 32 + lg * 8);
    __builtin_amdgcn_s_setprio(1);
    #pragma unroll
    for (int dt = 0; dt < 2; ++dt)
      #pragma unroll
      for (int qt = 0; qt < 2; ++qt)
        o[dt][qt] = __builtin_amdgcn_mfma_f32_16x16x32_bf16(vb[dt], pa[qt], o[dt][qt], 0, 0, 0);
    __builtin_amdgcn_s_setprio(0);
  }

  // -- O^T -> Ol[q][c] (bias already folded into V in K1) -------------------
  #pragma unroll
  for (int dt = 0; dt < 2; ++dt) {
    int c0 = h * 32 + dt * 16 + lg * 4;
    #pragma unroll
    for (int qt = 0; qt < 2; ++qt) {
      int q = qh * 32 + qt * 16 + lr;
      s16x4 sv;
      sv[0] = f2bf(o[dt][qt][0]);
      sv[1] = f2bf(o[dt][qt][1]);
      sv[2] = f2bf(o[dt][qt][2]);
      sv[3] = f2bf(o[dt][qt][3]);
      *(s16x4*)(&Ol[q * 256 + ((((c0 >> 3) ^ (q & 7)) << 3)) + (c0 & 7)]) = sv;
    }
  }
  __syncthreads();                                    // the ONLY barrier

  // -- proj: out = O @ proj_w^T + proj_b (swapped -> float4 stores) ---------
  const int cs = w >> 1;                              // 32-col strip 0..7
  f32x4 po[2][2] = {};
  const short* wpb = wp_b + (cs * 32) * 256;
  #pragma unroll 2
  for (int kk = 0; kk < 8; ++kk) {
    bf16x8 of[2], wf2[2];
    #pragma unroll
    for (int qt = 0; qt < 2; ++qt) {
      int q = qh * 32 + qt * 16 + lr;
      of[qt] = *(const bf16x8*)(&Ol[q * 256 + (((kk * 4 + lg) ^ (q & 7)) << 3)]);
    }
    #pragma unroll
    for (int mt = 0; mt < 2; ++mt)
      wf2[mt] = *(const bf16x8*)(wpb + (mt * 16 + lr) * 256 + kk * 32 + lg * 8);
    __builtin_amdgcn_s_setprio(1);
    #pragma unroll
    for (int mt = 0; mt < 2; ++mt)
      #pragma unroll
      for (int qt = 0; qt < 2; ++qt)
        po[mt][qt] = __builtin_amdgcn_mfma_f32_16x16x32_bf16(wf2[mt], of[qt], po[mt][qt], 0, 0, 0);
    __builtin_amdgcn_s_setprio(0);
  }
  float* od = out + (long)b * 49 * 256;
  #pragma unroll
  for (int mt = 0; mt < 2; ++mt) {
    int c0 = cs * 32 + mt * 16 + lg * 4;
    float4 pb = *(const float4*)(proj_b + c0);
    #pragma unroll
    for (int qt = 0; qt < 2; ++qt) {
      int q = qh * 32 + qt * 16 + lr;
      if (q < 49) {
        float4 ov;
        ov.x = po[mt][qt][0] + pb.x;
        ov.y = po[mt][qt][1] + pb.y;
        ov.z = po[mt][qt][2] + pb.z;
        ov.w = po[mt][qt][3] + pb.w;
        *(float4*)(od + q * 256 + c0) = ov;
      }
    }
  }
}

// ---------------- fallback: round-4 fused kernel (355 us, proven) -----------
__global__ __launch_bounds__(1024, 4) void fused_win(
    const float* __restrict__ x, const short* __restrict__ q_b,
    const short* __restrict__ wq_b, const short* __restrict__ wp_b,
    const float* __restrict__ qkv_b, const float* __restrict__ proj_b,
    const float* __restrict__ biasg, float* __restrict__ out)
{
  __shared__ __align__(16) char smem[81920];
  short* As = (short*)smem;
  short* Kl = (short*)(smem + 16384);
  short* vT = (short*)(smem + 49152);
  short* Ol = (short*)(smem + 49152);

  const int tid = threadIdx.x;
  const int b   = blockIdx.x;
  const int lane = tid & 63;
  const int w   = tid >> 6;
  const int lr  = lane & 15;
  const int lg  = lane >> 4;

  const float* xsrc = x + (long)b * 49 * 256;
  const int xrow = tid >> 4, xs = tid & 15;
  {
    bf16x8 v = {};
    if (xrow < 49) {
      const float4* p = (const float4*)(xsrc + xrow * 256 + xs * 8);
      v = pack8(p[0], p[1]);
    }
    *(bf16x8*)(&As[xrow * 128 + ((xs ^ (xrow & 7)) << 3)]) = v;
  }
  float4 h1a = make_float4(0, 0, 0, 0), h1b = make_float4(0, 0, 0, 0);
  if (xrow < 49) {
    const float4* p = (const float4*)(xsrc + xrow * 256 + 128 + xs * 8);
    h1a = p[0]; h1b = p[1];
  }
  __syncthreads();

  const bool isK = (w < 8);
  f32x4 acc[8] = {};
  const short* wbase = wq_b + ((isK ? 0 : 256) + (w & 7) * 32) * 256;

  #pragma unroll
  for (int kk = 0; kk < 4; ++kk) {
    bf16x8 xa[4], wf[2];
    #pragma unroll
    for (int t = 0; t < 4; ++t)
      xa[t] = *(const bf16x8*)(&As[(t * 16 + lr) * 128 + (((kk * 4 + lg) ^ (lr & 7)) << 3)]);
    #pragma unroll
    for (int t = 0; t < 2; ++t)
      wf[t] = *(const bf16x8*)(wbase + (t * 16 + lr) * 256 + kk * 32 + lg * 8);
    __builtin_amdgcn_s_setprio(1);
    if (isK) {
      #pragma unroll
      for (int mt = 0; mt < 2; ++mt)
        #pragma unroll
        for (int nt = 0; nt < 4; ++nt)
          acc[mt * 4 + nt] = __builtin_amdgcn_mfma_f32_16x16x32_bf16(wf[mt], xa[nt], acc[mt * 4 + nt], 0, 0, 0);
    } else {
      #pragma unroll
      for (int mt = 0; mt < 4; ++mt)
        #pragma unroll
        for (int nt = 0; nt < 2; ++nt)
          acc[mt * 2 + nt] = __builtin_amdgcn_mfma_f32_16x16x32_bf16(xa[mt], wf[nt], acc[mt * 2 + nt], 0, 0, 0);
    }
    __builtin_amdgcn_s_setprio(0);
  }
  __syncthreads();
  *(bf16x8*)(&As[xrow * 128 + ((xs ^ (xrow & 7)) << 3)]) = pack8(h1a, h1b);
  __syncthreads();
  #pragma unroll
  for (int kk = 0; kk < 4; ++kk) {
    bf16x8 xa[4], wf[2];
    #pragma unroll
    for (int t = 0; t < 4; ++t)
      xa[t] = *(const bf16x8*)(&As[(t * 16 + lr) * 128 + (((kk * 4 + lg) ^ (lr & 7)) << 3)]);
    #pragma unroll
    for (int t = 0; t < 2; ++t)
      wf[t] = *(const bf16x8*)(wbase + (t * 16 + lr) * 256 + 128 + kk * 32 + lg * 8);
    __builtin_amdgcn_s_setprio(1);
    if (isK) {
      #pragma unroll
      for (int mt = 0; mt < 2; ++mt)
        #pragma unroll
        for (int nt = 0; nt < 4; ++nt)
          acc[mt * 4 + nt] = __builtin_amdgcn_mfma_f32_16x16x32_bf16(wf[mt], xa[nt], acc[mt * 4 + nt], 0, 0, 0);
    } else {
      #pragma unroll
      for (int mt = 0; mt < 4; ++mt)
        #pragma unroll
        for (int nt = 0; nt < 2; ++nt)
          acc[mt * 2 + nt] = __builtin_amdgcn_mfma_f32_16x16x32_bf16(xa[mt], wf[nt], acc[mt * 2 + nt], 0, 0, 0);
    }
    __builtin_amdgcn_s_setprio(0);
  }

  if (isK) {
    #pragma unroll
    for (int mt = 0; mt < 2; ++mt) {
      int c0 = w * 32 + mt * 16 + lg * 4;
      float4 bv = *(const float4*)(qkv_b + c0);
      #pragma unroll
      for (int nt = 0; nt < 4; ++nt) {
        int key = nt * 16 + lr;
        s16x4 sv;
        sv[0] = f2bf(acc[mt * 4 + nt][0] + bv.x);
        sv[1] = f2bf(acc[mt * 4 + nt][1] + bv.y);
        sv[2] = f2bf(acc[mt * 4 + nt][2] + bv.z);
        sv[3] = f2bf(acc[mt * 4 + nt][3] + bv.w);
        *(s16x4*)(&Kl[key * 256 + ((((c0 >> 3) ^ (key & 7)) << 3)) + (c0 & 7)]) = sv;
      }
    }
  } else {
    #pragma unroll
    for (int nt = 0; nt < 2; ++nt) {
      int d = (w - 8) * 32 + nt * 16 + lr;
      float bv = qkv_b[256 + d];
      #pragma unroll
      for (int mt = 0; mt < 4; ++mt) {
        int key0 = mt * 16 + lg * 4;
        s16x4 sv;
        sv[0] = f2bf(acc[mt * 2 + nt][0] + bv);
        sv[1] = f2bf(acc[mt * 2 + nt][1] + bv);
        sv[2] = f2bf(acc[mt * 2 + nt][2] + bv);
        sv[3] = f2bf(acc[mt * 2 + nt][3] + bv);
        *(s16x4*)(&vT[d * 64 + ((((key0 >> 3) ^ (d & 7)) << 3)) + (key0 & 7)]) = sv;
      }
    }
  }
  __syncthreads();

  const int h = w >> 1, qh = w & 1;
  f32x4 st[4][2] = {};
  {
    const short* qsrc = q_b + ((long)(b >> 6) * 8 + h) * 2048 + qh * 1024;
    bf16x8 qa[2], kb[4];
    #pragma unroll
    for (int qt = 0; qt < 2; ++qt)
      qa[qt] = *(const bf16x8*)(qsrc + (qt * 16 + lr) * 32 + lg * 8);
    #pragma unroll
    for (int kt = 0; kt < 4; ++kt) {
      int key = kt * 16 + lr;
      kb[kt] = *(const bf16x8*)(&Kl[key * 256 + (((h * 4 + lg) ^ (key & 7)) << 3)]);
    }
    __builtin_amdgcn_s_setprio(1);
    #pragma unroll
    for (int kt = 0; kt < 4; ++kt)
      #pragma unroll
      for (int qt = 0; qt < 2; ++qt)
        st[kt][qt] = __builtin_amdgcn_mfma_f32_16x16x32_bf16(kb[kt], qa[qt], st[kt][qt], 0, 0, 0);
    __builtin_amdgcn_s_setprio(0);
  }

  {
    const float* bh = biasg + h * 4096;
    const float sc = 0.17677669529663687f;
    #pragma unroll
    for (int qt = 0; qt < 2; ++qt) {
      int q = qh * 32 + qt * 16 + lr;
      float mx = -1e30f;
      #pragma unroll
      for (int kt = 0; kt < 4; ++kt) {
        int key0 = kt * 16 + lg * 4;
        float4 bv = *(const float4*)(bh + q * 64 + key0);
        #pragma unroll
        for (int r = 0; r < 4; ++r) {
          float t = st[kt][qt][r] * sc + ((r == 0) ? bv.x : (r == 1) ? bv.y : (r == 2) ? bv.z : bv.w);
          if (key0 + r >= 49) t = -1e30f;
          st[kt][qt][r] = t;
          mx = fmaxf(mx, t);
        }
      }
      mx = fmaxf(mx, __shfl_xor(mx, 16));
      mx = fmaxf(mx, __shfl_xor(mx, 32));
      float sum = 0.f;
      #pragma unroll
      for (int kt = 0; kt < 4; ++kt)
        #pragma unroll
        for (int r = 0; r < 4; ++r) {
          float e = __expf(st[kt][qt][r] - mx);
          st[kt][qt][r] = e; sum += e;
        }
      sum += __shfl_xor(sum, 16);
      sum += __shfl_xor(sum, 32);
      float rinv = 1.f / sum;
      #pragma unroll
      for (int kt = 0; kt < 4; ++kt)
        #pragma unroll
        for (int r = 0; r < 4; ++r) st[kt][qt][r] *= rinv;
    }
  }

  short* Pw = (short*)(smem + 16384 + w * 2048);
  f32x4 o[2][2] = {};
  #pragma unroll
  for (int ks = 0; ks < 2; ++ks) {
    #pragma unroll
    for (int kh = 0; kh < 2; ++kh) {
      int kt = ks * 2 + kh;
      int kloc0 = kh * 16 + lg * 4;
      #pragma unroll
      for (int qt = 0; qt < 2; ++qt) {
        int qloc = qt * 16 + lr;
        s16x4 sv;
        sv[0] = f2bf(st[kt][qt][0]);
        sv[1] = f2bf(st[kt][qt][1]);
        sv[2] = f2bf(st[kt][qt][2]);
        sv[3] = f2bf(st[kt][qt][3]);
        *(s16x4*)(&Pw[qloc * 32 + ((((kloc0 >> 3) ^ ((qloc >> 1) & 3)) << 3)) + (kloc0 & 7)]) = sv;
      }
    }
    bf16x8 pa[2], vb[2];
    #pragma unroll
    for (int qt = 0; qt < 2; ++qt) {
      int qloc = qt * 16 + lr;
      pa[qt] = *(const bf16x8*)(&Pw[qloc * 32 + ((lg ^ ((qloc >> 1) & 3)) << 3)]);
    }
    #pragma unroll
    for (int dt = 0; dt < 2; ++dt) {
      int d = h * 32 + dt * 16 + lr;
      vb[dt] = *(const bf16x8*)(&vT[d * 64 + (((ks * 4 + lg) ^ (d & 7)) << 3)]);
    }
    __builtin_amdgcn_s_setprio(1);
    #pragma unroll
    for (int dt = 0; dt < 2; ++dt)
      #pragma unroll
      for (int qt = 0; qt < 2; ++qt)
        o[dt][qt] = __builtin_amdgcn_mfma_f32_16x16x32_bf16(vb[dt], pa[qt], o[dt][qt], 0, 0, 0);
    __builtin_amdgcn_s_setprio(0);
  }
  __syncthreads();

  #pragma unroll
  for (int dt = 0; dt < 2; ++dt) {
    int c0 = h * 32 + dt * 16 + lg * 4;
    #pragma unroll
    for (int qt = 0; qt < 2; ++qt) {
      int q = qh * 32 + qt * 16 + lr;
      s16x4 sv;
      sv[0] = f2bf(o[dt][qt][0]);
      sv[1] = f2bf(o[dt][qt][1]);
      sv[2] = f2bf(o[dt][qt][2]);
      sv[3] = f2bf(o[dt][qt][3]);
      *(s16x4*)(&Ol[q * 256 + ((((c0 >> 3) ^ (q & 7)) << 3)) + (c0 & 7)]) = sv;
    }
  }
  __syncthreads();

  const int cs = w >> 1;
  f32x4 po[2][2] = {};
  const short* wpb = wp_b + (cs * 32) * 256;
  #pragma unroll 2
  for (int kk = 0; kk < 8; ++kk) {
    bf16x8 of[2], wf2[2];
    #pragma unroll
    for (int qt = 0; qt < 2; ++qt) {
      int q = qh * 32 + qt * 16 + lr;
      of[qt] = *(const bf16x8*)(&Ol[q * 256 + (((kk * 4 + lg) ^ (q & 7)) << 3)]);
    }
    #pragma unroll
    for (int mt = 0; mt < 2; ++mt)
      wf2[mt] = *(const bf16x8*)(wpb + (mt * 16 + lr) * 256 + kk * 32 + lg * 8);
    __builtin_amdgcn_s_setprio(1);
    #pragma unroll
    for (int mt = 0; mt < 2; ++mt)
      #pragma unroll
      for (int qt = 0; qt < 2; ++qt)
        po[mt][qt] = __builtin_amdgcn_mfma_f32_16x16x32_bf16(wf2[mt], of[qt], po[mt][qt], 0, 0, 0);
    __builtin_amdgcn_s_setprio(0);
  }
  float* od = out + (long)b * 49 * 256;
  #pragma unroll
  for (int mt = 0; mt < 2; ++mt) {
    int c0 = cs * 32 + mt * 16 + lg * 4;
    float4 pb = *(const float4*)(proj_b + c0);
    #pragma unroll
    for (int qt = 0; qt < 2; ++qt) {
      int q = qh * 32 + qt * 16 + lr;
      if (q < 49) {
        float4 ov;
        ov.x = po[mt][qt][0] + pb.x;
        ov.y = po[mt][qt][1] + pb.y;
        ov.z = po[mt][qt][2] + pb.z;
        ov.w = po[mt][qt][3] + pb.w;
        *(float4*)(od + q * 256 + c0) = ov;
      }
    }
  }
}

extern "C" void kernel_launch(void* const* d_in, const int* in_sizes, int n_in,
                              void* d_out, int out_size, void* d_ws, size_t ws_size,
                              hipStream_t stream) {
  const float* x      = (const float*)d_in[0];
  const float* qg     = (const float*)d_in[1];
  const float* qkv_w  = (const float*)d_in[2];
  const float* qkv_b  = (const float*)d_in[3];
  const float* proj_w = (const float*)d_in[4];
  const float* proj_b = (const float*)d_in[5];
  const float* table  = (const float*)d_in[6];
  float* out = (float*)d_out;

  char* ws = (char*)d_ws;
  short* wq_b  = (short*)ws;              // 262144 B  bf16 qkv_w [512][256]
  short* wp_b  = (short*)(ws + 262144);   // 131072 B  bf16 proj_w [256][256]
  short* q_b   = (short*)(ws + 393216);   // 2097152 B bf16 q padded [64][8][64][32]
  float* biasg = (float*)(ws + 2490368);  // 131072 B  f32 bias padded [8][64][64]
  // split-path extras:
  short* Kg  = (short*)(ws + 2621440);                // 134217728 B [4096][64][256]
  short* vTg = (short*)(ws + 2621440 + 134217728ULL); // 134217728 B [4096][256][64]
  const size_t NEED = 2621440ULL + 2ULL * 134217728ULL;  // ~271 MB

  const int prep_total = 131072 + 65536 + 1048576 + 32768;
  prep_kernel<<<(prep_total + 255) / 256, 256, 0, stream>>>(
      qkv_w, proj_w, qg, table, wq_b, wp_b, q_b, biasg);

  if (ws_size >= NEED) {
    kv_win<<<4096, 512, 0, stream>>>(x, wq_b, qkv_b, Kg, vTg);
    attn_win<<<4096, 1024, 0, stream>>>(Kg, vTg, q_b, wp_b, proj_b, biasg, out);
  } else {
    fused_win<<<4096, 1024, 0, stream>>>(x, q_b, wq_b, wp_b, qkv_b, proj_b, biasg, out);
  }
}

// Round 8
// 498.253 us; speedup vs baseline: 1.8442x; 1.8442x over previous
//
#include <hip/hip_runtime.h>

typedef __attribute__((ext_vector_type(4))) float f32x4;
typedef __attribute__((ext_vector_type(8))) short bf16x8;
typedef __attribute__((ext_vector_type(4))) short s16x4;

__device__ __forceinline__ short f2bf(float f) {
  union { float f; unsigned u; } x; x.f = f;
  return (short)((x.u + 0x7fffu + ((x.u >> 16) & 1u)) >> 16);   // RNE
}

__device__ __forceinline__ bf16x8 pack8(float4 a, float4 b) {
  bf16x8 v;
  v[0] = f2bf(a.x); v[1] = f2bf(a.y); v[2] = f2bf(a.z); v[3] = f2bf(a.w);
  v[4] = f2bf(b.x); v[5] = f2bf(b.y); v[6] = f2bf(b.z); v[7] = f2bf(b.w);
  return v;
}

// ---------------- prep: weights->bf16, q padded->bf16, bias [8][64][64] -----
__global__ __launch_bounds__(256) void prep_kernel(
    const float* __restrict__ qkv_w, const float* __restrict__ proj_w,
    const float* __restrict__ qg, const float* __restrict__ table,
    short* __restrict__ wq_b, short* __restrict__ wp_b,
    short* __restrict__ q_b, float* __restrict__ biasg)
{
  int idx = blockIdx.x * 256 + threadIdx.x;
  if (idx < 131072) { wq_b[idx] = f2bf(qkv_w[idx]); return; }
  idx -= 131072;
  if (idx < 65536) { wp_b[idx] = f2bf(proj_w[idx]); return; }
  idx -= 65536;
  if (idx < 1048576) {                       // q padded: [64 win][8 h][64 n][32 d]
    int d = idx & 31, n = (idx >> 5) & 63, hh = (idx >> 11) & 7, w = idx >> 14;
    float v = (n < 49) ? qg[((w * 8 + hh) * 49 + n) * 32 + d] : 0.f;
    q_b[idx] = f2bf(v);
    return;
  }
  idx -= 1048576;
  if (idx < 32768) {                         // bias padded: [8 h][64 q][64 k]
    int hh = idx >> 12, rem = idx & 4095;
    int q = rem >> 6, k = rem & 63;
    float v = 0.f;
    if (q < 49 && k < 49) {
      int di = q / 7 - k / 7 + 6, dj = q % 7 - k % 7 + 6;
      v = table[(di * 13 + dj) * 8 + hh];
    }
    biasg[idx] = v;
  }
}

// ---------------- K1: kv GEMM (r4 phase-0/1, proven no-spill) ---------------
// block = 1 window, 1024 thr = 16 waves. waves 0-7: K (swapped, 32-col strip);
// waves 8-15: V. Epilogue -> global, PER-HEAD layouts for coalesced K2 reads:
//   Kg [win][h][64 key][32 c]        (K fragment = 1KB contiguous per wave)
//   vTg[win][h][2 ks][32 d][32 key]  (V fragment = 1KB contiguous per wave)
__global__ __launch_bounds__(1024, 4) void kv_win(
    const float* __restrict__ x, const short* __restrict__ wq_b,
    const float* __restrict__ qkv_b,
    short* __restrict__ Kg, short* __restrict__ vTg)
{
  __shared__ __align__(16) short As[64 * 128];        // 16 KiB half-tile
  const int tid = threadIdx.x, b = blockIdx.x;
  const int lane = tid & 63, w = tid >> 6;
  const int lr = lane & 15, lg = lane >> 4;

  const float* xsrc = x + (long)b * 49 * 256;
  const int xrow = tid >> 4, xs = tid & 15;
  {
    bf16x8 v = {};
    if (xrow < 49) {
      const float4* p = (const float4*)(xsrc + xrow * 256 + xs * 8);
      v = pack8(p[0], p[1]);
    }
    *(bf16x8*)(&As[xrow * 128 + ((xs ^ (xrow & 7)) << 3)]) = v;
  }
  float4 h1a = make_float4(0, 0, 0, 0), h1b = make_float4(0, 0, 0, 0);
  if (xrow < 49) {
    const float4* p = (const float4*)(xsrc + xrow * 256 + 128 + xs * 8);
    h1a = p[0]; h1b = p[1];
  }
  __syncthreads();

  const bool isK = (w < 8);
  f32x4 acc[8] = {};
  const short* wbase = wq_b + ((isK ? 0 : 256) + (w & 7) * 32) * 256;

  #pragma unroll
  for (int kk = 0; kk < 4; ++kk) {                    // K-half 0
    bf16x8 xa[4], wf[2];
    #pragma unroll
    for (int t = 0; t < 4; ++t)
      xa[t] = *(const bf16x8*)(&As[(t * 16 + lr) * 128 + (((kk * 4 + lg) ^ (lr & 7)) << 3)]);
    #pragma unroll
    for (int t = 0; t < 2; ++t)
      wf[t] = *(const bf16x8*)(wbase + (t * 16 + lr) * 256 + kk * 32 + lg * 8);
    __builtin_amdgcn_s_setprio(1);
    if (isK) {
      #pragma unroll
      for (int mt = 0; mt < 2; ++mt)
        #pragma unroll
        for (int nt = 0; nt < 4; ++nt)
          acc[mt * 4 + nt] = __builtin_amdgcn_mfma_f32_16x16x32_bf16(wf[mt], xa[nt], acc[mt * 4 + nt], 0, 0, 0);
    } else {
      #pragma unroll
      for (int mt = 0; mt < 4; ++mt)
        #pragma unroll
        for (int nt = 0; nt < 2; ++nt)
          acc[mt * 2 + nt] = __builtin_amdgcn_mfma_f32_16x16x32_bf16(xa[mt], wf[nt], acc[mt * 2 + nt], 0, 0, 0);
    }
    __builtin_amdgcn_s_setprio(0);
  }
  __syncthreads();
  *(bf16x8*)(&As[xrow * 128 + ((xs ^ (xrow & 7)) << 3)]) = pack8(h1a, h1b);
  __syncthreads();
  #pragma unroll
  for (int kk = 0; kk < 4; ++kk) {                    // K-half 1
    bf16x8 xa[4], wf[2];
    #pragma unroll
    for (int t = 0; t < 4; ++t)
      xa[t] = *(const bf16x8*)(&As[(t * 16 + lr) * 128 + (((kk * 4 + lg) ^ (lr & 7)) << 3)]);
    #pragma unroll
    for (int t = 0; t < 2; ++t)
      wf[t] = *(const bf16x8*)(wbase + (t * 16 + lr) * 256 + 128 + kk * 32 + lg * 8);
    __builtin_amdgcn_s_setprio(1);
    if (isK) {
      #pragma unroll
      for (int mt = 0; mt < 2; ++mt)
        #pragma unroll
        for (int nt = 0; nt < 4; ++nt)
          acc[mt * 4 + nt] = __builtin_amdgcn_mfma_f32_16x16x32_bf16(wf[mt], xa[nt], acc[mt * 4 + nt], 0, 0, 0);
    } else {
      #pragma unroll
      for (int mt = 0; mt < 4; ++mt)
        #pragma unroll
        for (int nt = 0; nt < 2; ++nt)
          acc[mt * 2 + nt] = __builtin_amdgcn_mfma_f32_16x16x32_bf16(xa[mt], wf[nt], acc[mt * 2 + nt], 0, 0, 0);
    }
    __builtin_amdgcn_s_setprio(0);
  }

  // epilogue -> global (+qkv_b), b64 writes
  if (isK) {        // h = w; lane: c32 = mt*16+lg*4 (+r), key = nt*16+lr
    #pragma unroll
    for (int mt = 0; mt < 2; ++mt) {
      int c0 = w * 32 + mt * 16 + lg * 4;
      float4 bv = *(const float4*)(qkv_b + c0);
      #pragma unroll
      for (int nt = 0; nt < 4; ++nt) {
        int key = nt * 16 + lr;
        s16x4 sv;
        sv[0] = f2bf(acc[mt * 4 + nt][0] + bv.x);
        sv[1] = f2bf(acc[mt * 4 + nt][1] + bv.y);
        sv[2] = f2bf(acc[mt * 4 + nt][2] + bv.z);
        sv[3] = f2bf(acc[mt * 4 + nt][3] + bv.w);
        *(s16x4*)(Kg + (((long)b * 8 + w) * 64 + key) * 32 + mt * 16 + lg * 4) = sv;
      }
    }
  } else {          // h = w-8; lane: d32 = nt*16+lr, key = mt*16+lg*4 (+r)
    #pragma unroll
    for (int nt = 0; nt < 2; ++nt) {
      int d = (w - 8) * 32 + nt * 16 + lr;
      float bv = qkv_b[256 + d];
      #pragma unroll
      for (int mt = 0; mt < 4; ++mt) {
        int ks = mt >> 1, k32 = (mt & 1) * 16 + lg * 4;
        s16x4 sv;
        sv[0] = f2bf(acc[mt * 2 + nt][0] + bv);
        sv[1] = f2bf(acc[mt * 2 + nt][1] + bv);
        sv[2] = f2bf(acc[mt * 2 + nt][2] + bv);
        sv[3] = f2bf(acc[mt * 2 + nt][3] + bv);
        *(s16x4*)(vTg + ((((long)b * 8 + (w - 8)) * 2 + ks) * 32 + nt * 16 + lr) * 32 + k32) = sv;
      }
    }
  }
}

// ---------------- K2: attention + proj, coalesced K/V from global -----------
// block = 1 window, 1024 thr = 16 waves, wave = (head h, q-half qh). 1 barrier.
__global__ __launch_bounds__(1024, 4) void attn_win(
    const short* __restrict__ Kg, const short* __restrict__ vTg,
    const short* __restrict__ q_b, const short* __restrict__ wp_b,
    const float* __restrict__ proj_b, const float* __restrict__ biasg,
    float* __restrict__ out)
{
  __shared__ __align__(16) char smem[65536];
  short* Ol = (short*)smem;                           // [64 q][256 c]
  const int tid = threadIdx.x, b = blockIdx.x;
  const int lane = tid & 63, w = tid >> 6;            // 0..15
  const int lr = lane & 15, lg = lane >> 4;
  short* Pw = (short*)(smem + 32768 + w * 2048);      // per-wave [32 q][32 k]

  const int h = w >> 1, qh = w & 1;

  // hoisted independent loads: K, Q, V fragments (all 1KB-contiguous/wave)
  bf16x8 qa[2], kb[4], vb[2][2];
  {
    const short* qsrc = q_b + ((long)(b >> 6) * 8 + h) * 2048 + qh * 1024;
    #pragma unroll
    for (int qt = 0; qt < 2; ++qt)
      qa[qt] = *(const bf16x8*)(qsrc + (qt * 16 + lr) * 32 + lg * 8);
    const short* kh_ = Kg + ((long)b * 8 + h) * 2048;
    #pragma unroll
    for (int kt = 0; kt < 4; ++kt)
      kb[kt] = *(const bf16x8*)(kh_ + (kt * 16 + lr) * 32 + lg * 8);
    const short* vh_ = vTg + ((long)b * 8 + h) * 2048;
    #pragma unroll
    for (int ks = 0; ks < 2; ++ks)
      #pragma unroll
      for (int dt = 0; dt < 2; ++dt)
        vb[ks][dt] = *(const bf16x8*)(vh_ + (ks * 32 + dt * 16 + lr) * 32 + lg * 8);
  }

  // -- S^T = mfma(K, Q): st[kt][qt], lane holds S[q=qt*16+lr][key=kt*16+lg*4+r]
  f32x4 st[4][2] = {};
  __builtin_amdgcn_s_setprio(1);
  #pragma unroll
  for (int kt = 0; kt < 4; ++kt)
    #pragma unroll
    for (int qt = 0; qt < 2; ++qt)
      st[kt][qt] = __builtin_amdgcn_mfma_f32_16x16x32_bf16(kb[kt], qa[qt], st[kt][qt], 0, 0, 0);
  __builtin_amdgcn_s_setprio(0);

  // -- softmax; row q = qh*32+qt*16+lr, keys in-lane (2 shfls per reduce) ---
  {
    const float* bh = biasg + h * 4096;
    const float sc = 0.17677669529663687f;            // 32^-0.5
    #pragma unroll
    for (int qt = 0; qt < 2; ++qt) {
      int q = qh * 32 + qt * 16 + lr;
      float mx = -1e30f;
      #pragma unroll
      for (int kt = 0; kt < 4; ++kt) {
        int key0 = kt * 16 + lg * 4;
        float4 bv = *(const float4*)(bh + q * 64 + key0);
        #pragma unroll
        for (int r = 0; r < 4; ++r) {
          float t = st[kt][qt][r] * sc + ((r == 0) ? bv.x : (r == 1) ? bv.y : (r == 2) ? bv.z : bv.w);
          if (key0 + r >= 49) t = -1e30f;
          st[kt][qt][r] = t;
          mx = fmaxf(mx, t);
        }
      }
      mx = fmaxf(mx, __shfl_xor(mx, 16));
      mx = fmaxf(mx, __shfl_xor(mx, 32));
      float sum = 0.f;
      #pragma unroll
      for (int kt = 0; kt < 4; ++kt)
        #pragma unroll
        for (int r = 0; r < 4; ++r) {
          float e = __expf(st[kt][qt][r] - mx);
          st[kt][qt][r] = e; sum += e;
        }
      sum += __shfl_xor(sum, 16);
      sum += __shfl_xor(sum, 32);
      float rinv = 1.f / sum;                         // fold 1/sum into P
      #pragma unroll
      for (int kt = 0; kt < 4; ++kt)
        #pragma unroll
        for (int r = 0; r < 4; ++r) st[kt][qt][r] *= rinv;
    }
  }

  // -- PV: O^T = mfma(V^T, P^T); P bounced through private per-wave LDS -----
  f32x4 o[2][2] = {};
  #pragma unroll
  for (int ks = 0; ks < 2; ++ks) {
    #pragma unroll
    for (int kh = 0; kh < 2; ++kh) {
      int kt = ks * 2 + kh;
      int kloc0 = kh * 16 + lg * 4;
      #pragma unroll
      for (int qt = 0; qt < 2; ++qt) {
        int qloc = qt * 16 + lr;
        s16x4 sv;
        sv[0] = f2bf(st[kt][qt][0]);
        sv[1] = f2bf(st[kt][qt][1]);
        sv[2] = f2bf(st[kt][qt][2]);
        sv[3] = f2bf(st[kt][qt][3]);
        *(s16x4*)(&Pw[qloc * 32 + ((((kloc0 >> 3) ^ ((qloc >> 1) & 3)) << 3)) + (kloc0 & 7)]) = sv;
      }
    }
    bf16x8 pa[2];
    #pragma unroll
    for (int qt = 0; qt < 2; ++qt) {
      int qloc = qt * 16 + lr;
      pa[qt] = *(const bf16x8*)(&Pw[qloc * 32 + ((lg ^ ((qloc >> 1) & 3)) << 3)]);
    }
    __builtin_amdgcn_s_setprio(1);
    #pragma unroll
    for (int dt = 0; dt < 2; ++dt)
      #pragma unroll
      for (int qt = 0; qt < 2; ++qt)
        o[dt][qt] = __builtin_amdgcn_mfma_f32_16x16x32_bf16(vb[ks][dt], pa[qt], o[dt][qt], 0, 0, 0);
    __builtin_amdgcn_s_setprio(0);
  }

  // -- O^T -> Ol[q][c] (v-bias already folded in K1) ------------------------
  #pragma unroll
  for (int dt = 0; dt < 2; ++dt) {
    int c0 = h * 32 + dt * 16 + lg * 4;
    #pragma unroll
    for (int qt = 0; qt < 2; ++qt) {
      int q = qh * 32 + qt * 16 + lr;
      s16x4 sv;
      sv[0] = f2bf(o[dt][qt][0]);
      sv[1] = f2bf(o[dt][qt][1]);
      sv[2] = f2bf(o[dt][qt][2]);
      sv[3] = f2bf(o[dt][qt][3]);
      *(s16x4*)(&Ol[q * 256 + ((((c0 >> 3) ^ (q & 7)) << 3)) + (c0 & 7)]) = sv;
    }
  }
  __syncthreads();                                    // the ONLY barrier

  // -- proj: out = O @ proj_w^T + proj_b (swapped -> float4 stores) ---------
  const int cs = w >> 1;                              // 32-col strip 0..7
  f32x4 po[2][2] = {};
  const short* wpb = wp_b + (cs * 32) * 256;
  #pragma unroll 2
  for (int kk = 0; kk < 8; ++kk) {
    bf16x8 of[2], wf2[2];
    #pragma unroll
    for (int qt = 0; qt < 2; ++qt) {
      int q = qh * 32 + qt * 16 + lr;
      of[qt] = *(const bf16x8*)(&Ol[q * 256 + (((kk * 4 + lg) ^ (q & 7)) << 3)]);
    }
    #pragma unroll
    for (int mt = 0; mt < 2; ++mt)
      wf2[mt] = *(const bf16x8*)(wpb + (mt * 16 + lr) * 256 + kk * 32 + lg * 8);
    __builtin_amdgcn_s_setprio(1);
    #pragma unroll
    for (int mt = 0; mt < 2; ++mt)
      #pragma unroll
      for (int qt = 0; qt < 2; ++qt)
        po[mt][qt] = __builtin_amdgcn_mfma_f32_16x16x32_bf16(wf2[mt], of[qt], po[mt][qt], 0, 0, 0);
    __builtin_amdgcn_s_setprio(0);
  }
  float* od = out + (long)b * 49 * 256;
  #pragma unroll
  for (int mt = 0; mt < 2; ++mt) {
    int c0 = cs * 32 + mt * 16 + lg * 4;
    float4 pb = *(const float4*)(proj_b + c0);
    #pragma unroll
    for (int qt = 0; qt < 2; ++qt) {
      int q = qh * 32 + qt * 16 + lr;
      if (q < 49) {
        float4 ov;
        ov.x = po[mt][qt][0] + pb.x;
        ov.y = po[mt][qt][1] + pb.y;
        ov.z = po[mt][qt][2] + pb.z;
        ov.w = po[mt][qt][3] + pb.w;
        *(float4*)(od + q * 256 + c0) = ov;
      }
    }
  }
}

// ---------------- fallback: round-4 fused kernel (355 us, proven) -----------
__global__ __launch_bounds__(1024, 4) void fused_win(
    const float* __restrict__ x, const short* __restrict__ q_b,
    const short* __restrict__ wq_b, const short* __restrict__ wp_b,
    const float* __restrict__ qkv_b, const float* __restrict__ proj_b,
    const float* __restrict__ biasg, float* __restrict__ out)
{
  __shared__ __align__(16) char smem[81920];
  short* As = (short*)smem;
  short* Kl = (short*)(smem + 16384);
  short* vT = (short*)(smem + 49152);
  short* Ol = (short*)(smem + 49152);

  const int tid = threadIdx.x;
  const int b   = blockIdx.x;
  const int lane = tid & 63;
  const int w   = tid >> 6;
  const int lr  = lane & 15;
  const int lg  = lane >> 4;

  const float* xsrc = x + (long)b * 49 * 256;
  const int xrow = tid >> 4, xs = tid & 15;
  {
    bf16x8 v = {};
    if (xrow < 49) {
      const float4* p = (const float4*)(xsrc + xrow * 256 + xs * 8);
      v = pack8(p[0], p[1]);
    }
    *(bf16x8*)(&As[xrow * 128 + ((xs ^ (xrow & 7)) << 3)]) = v;
  }
  float4 h1a = make_float4(0, 0, 0, 0), h1b = make_float4(0, 0, 0, 0);
  if (xrow < 49) {
    const float4* p = (const float4*)(xsrc + xrow * 256 + 128 + xs * 8);
    h1a = p[0]; h1b = p[1];
  }
  __syncthreads();

  const bool isK = (w < 8);
  f32x4 acc[8] = {};
  const short* wbase = wq_b + ((isK ? 0 : 256) + (w & 7) * 32) * 256;

  #pragma unroll
  for (int kk = 0; kk < 4; ++kk) {
    bf16x8 xa[4], wf[2];
    #pragma unroll
    for (int t = 0; t < 4; ++t)
      xa[t] = *(const bf16x8*)(&As[(t * 16 + lr) * 128 + (((kk * 4 + lg) ^ (lr & 7)) << 3)]);
    #pragma unroll
    for (int t = 0; t < 2; ++t)
      wf[t] = *(const bf16x8*)(wbase + (t * 16 + lr) * 256 + kk * 32 + lg * 8);
    __builtin_amdgcn_s_setprio(1);
    if (isK) {
      #pragma unroll
      for (int mt = 0; mt < 2; ++mt)
        #pragma unroll
        for (int nt = 0; nt < 4; ++nt)
          acc[mt * 4 + nt] = __builtin_amdgcn_mfma_f32_16x16x32_bf16(wf[mt], xa[nt], acc[mt * 4 + nt], 0, 0, 0);
    } else {
      #pragma unroll
      for (int mt = 0; mt < 4; ++mt)
        #pragma unroll
        for (int nt = 0; nt < 2; ++nt)
          acc[mt * 2 + nt] = __builtin_amdgcn_mfma_f32_16x16x32_bf16(xa[mt], wf[nt], acc[mt * 2 + nt], 0, 0, 0);
    }
    __builtin_amdgcn_s_setprio(0);
  }
  __syncthreads();
  *(bf16x8*)(&As[xrow * 128 + ((xs ^ (xrow & 7)) << 3)]) = pack8(h1a, h1b);
  __syncthreads();
  #pragma unroll
  for (int kk = 0; kk < 4; ++kk) {
    bf16x8 xa[4], wf[2];
    #pragma unroll
    for (int t = 0; t < 4; ++t)
      xa[t] = *(const bf16x8*)(&As[(t * 16 + lr) * 128 + (((kk * 4 + lg) ^ (lr & 7)) << 3)]);
    #pragma unroll
    for (int t = 0; t < 2; ++t)
      wf[t] = *(const bf16x8*)(wbase + (t * 16 + lr) * 256 + 128 + kk * 32 + lg * 8);
    __builtin_amdgcn_s_setprio(1);
    if (isK) {
      #pragma unroll
      for (int mt = 0; mt < 2; ++mt)
        #pragma unroll
        for (int nt = 0; nt < 4; ++nt)
          acc[mt * 4 + nt] = __builtin_amdgcn_mfma_f32_16x16x32_bf16(wf[mt], xa[nt], acc[mt * 4 + nt], 0, 0, 0);
    } else {
      #pragma unroll
      for (int mt = 0; mt < 4; ++mt)
        #pragma unroll
        for (int nt = 0; nt < 2; ++nt)
          acc[mt * 2 + nt] = __builtin_amdgcn_mfma_f32_16x16x32_bf16(xa[mt], wf[nt], acc[mt * 2 + nt], 0, 0, 0);
    }
    __builtin_amdgcn_s_setprio(0);
  }

  if (isK) {
    #pragma unroll
    for (int mt = 0; mt < 2; ++mt) {
      int c0 = w * 32 + mt * 16 + lg * 4;
      float4 bv = *(const float4*)(qkv_b + c0);
      #pragma unroll
      for (int nt = 0; nt < 4; ++nt) {
        int key = nt * 16 + lr;
        s16x4 sv;
        sv[0] = f2bf(acc[mt * 4 + nt][0] + bv.x);
        sv[1] = f2bf(acc[mt * 4 + nt][1] + bv.y);
        sv[2] = f2bf(acc[mt * 4 + nt][2] + bv.z);
        sv[3] = f2bf(acc[mt * 4 + nt][3] + bv.w);
        *(s16x4*)(&Kl[key * 256 + ((((c0 >> 3) ^ (key & 7)) << 3)) + (c0 & 7)]) = sv;
      }
    }
  } else {
    #pragma unroll
    for (int nt = 0; nt < 2; ++nt) {
      int d = (w - 8) * 32 + nt * 16 + lr;
      float bv = qkv_b[256 + d];
      #pragma unroll
      for (int mt = 0; mt < 4; ++mt) {
        int key0 = mt * 16 + lg * 4;
        s16x4 sv;
        sv[0] = f2bf(acc[mt * 2 + nt][0] + bv);
        sv[1] = f2bf(acc[mt * 2 + nt][1] + bv);
        sv[2] = f2bf(acc[mt * 2 + nt][2] + bv);
        sv[3] = f2bf(acc[mt * 2 + nt][3] + bv);
        *(s16x4*)(&vT[d * 64 + ((((key0 >> 3) ^ (d & 7)) << 3)) + (key0 & 7)]) = sv;
      }
    }
  }
  __syncthreads();

  const int h = w >> 1, qh = w & 1;
  f32x4 st[4][2] = {};
  {
    const short* qsrc = q_b + ((long)(b >> 6) * 8 + h) * 2048 + qh * 1024;
    bf16x8 qa[2], kb[4];
    #pragma unroll
    for (int qt = 0; qt < 2; ++qt)
      qa[qt] = *(const bf16x8*)(qsrc + (qt * 16 + lr) * 32 + lg * 8);
    #pragma unroll
    for (int kt = 0; kt < 4; ++kt) {
      int key = kt * 16 + lr;
      kb[kt] = *(const bf16x8*)(&Kl[key * 256 + (((h * 4 + lg) ^ (key & 7)) << 3)]);
    }
    __builtin_amdgcn_s_setprio(1);
    #pragma unroll
    for (int kt = 0; kt < 4; ++kt)
      #pragma unroll
      for (int qt = 0; qt < 2; ++qt)
        st[kt][qt] = __builtin_amdgcn_mfma_f32_16x16x32_bf16(kb[kt], qa[qt], st[kt][qt], 0, 0, 0);
    __builtin_amdgcn_s_setprio(0);
  }

  {
    const float* bh = biasg + h * 4096;
    const float sc = 0.17677669529663687f;
    #pragma unroll
    for (int qt = 0; qt < 2; ++qt) {
      int q = qh * 32 + qt * 16 + lr;
      float mx = -1e30f;
      #pragma unroll
      for (int kt = 0; kt < 4; ++kt) {
        int key0 = kt * 16 + lg * 4;
        float4 bv = *(const float4*)(bh + q * 64 + key0);
        #pragma unroll
        for (int r = 0; r < 4; ++r) {
          float t = st[kt][qt][r] * sc + ((r == 0) ? bv.x : (r == 1) ? bv.y : (r == 2) ? bv.z : bv.w);
          if (key0 + r >= 49) t = -1e30f;
          st[kt][qt][r] = t;
          mx = fmaxf(mx, t);
        }
      }
      mx = fmaxf(mx, __shfl_xor(mx, 16));
      mx = fmaxf(mx, __shfl_xor(mx, 32));
      float sum = 0.f;
      #pragma unroll
      for (int kt = 0; kt < 4; ++kt)
        #pragma unroll
        for (int r = 0; r < 4; ++r) {
          float e = __expf(st[kt][qt][r] - mx);
          st[kt][qt][r] = e; sum += e;
        }
      sum += __shfl_xor(sum, 16);
      sum += __shfl_xor(sum, 32);
      float rinv = 1.f / sum;
      #pragma unroll
      for (int kt = 0; kt < 4; ++kt)
        #pragma unroll
        for (int r = 0; r < 4; ++r) st[kt][qt][r] *= rinv;
    }
  }

  short* Pw = (short*)(smem + 16384 + w * 2048);
  f32x4 o[2][2] = {};
  #pragma unroll
  for (int ks = 0; ks < 2; ++ks) {
    #pragma unroll
    for (int kh = 0; kh < 2; ++kh) {
      int kt = ks * 2 + kh;
      int kloc0 = kh * 16 + lg * 4;
      #pragma unroll
      for (int qt = 0; qt < 2; ++qt) {
        int qloc = qt * 16 + lr;
        s16x4 sv;
        sv[0] = f2bf(st[kt][qt][0]);
        sv[1] = f2bf(st[kt][qt][1]);
        sv[2] = f2bf(st[kt][qt][2]);
        sv[3] = f2bf(st[kt][qt][3]);
        *(s16x4*)(&Pw[qloc * 32 + ((((kloc0 >> 3) ^ ((qloc >> 1) & 3)) << 3)) + (kloc0 & 7)]) = sv;
      }
    }
    bf16x8 pa[2], vb[2];
    #pragma unroll
    for (int qt = 0; qt < 2; ++qt) {
      int qloc = qt * 16 + lr;
      pa[qt] = *(const bf16x8*)(&Pw[qloc * 32 + ((lg ^ ((qloc >> 1) & 3)) << 3)]);
    }
    #pragma unroll
    for (int dt = 0; dt < 2; ++dt) {
      int d = h * 32 + dt * 16 + lr;
      vb[dt] = *(const bf16x8*)(&vT[d * 64 + (((ks * 4 + lg) ^ (d & 7)) << 3)]);
    }
    __builtin_amdgcn_s_setprio(1);
    #pragma unroll
    for (int dt = 0; dt < 2; ++dt)
      #pragma unroll
      for (int qt = 0; qt < 2; ++qt)
        o[dt][qt] = __builtin_amdgcn_mfma_f32_16x16x32_bf16(vb[dt], pa[qt], o[dt][qt], 0, 0, 0);
    __builtin_amdgcn_s_setprio(0);
  }
  __syncthreads();

  #pragma unroll
  for (int dt = 0; dt < 2; ++dt) {
    int c0 = h * 32 + dt * 16 + lg * 4;
    #pragma unroll
    for (int qt = 0; qt < 2; ++qt) {
      int q = qh * 32 + qt * 16 + lr;
      s16x4 sv;
      sv[0] = f2bf(o[dt][qt][0]);
      sv[1] = f2bf(o[dt][qt][1]);
      sv[2] = f2bf(o[dt][qt][2]);
      sv[3] = f2bf(o[dt][qt][3]);
      *(s16x4*)(&Ol[q * 256 + ((((c0 >> 3) ^ (q & 7)) << 3)) + (c0 & 7)]) = sv;
    }
  }
  __syncthreads();

  const int cs = w >> 1;
  f32x4 po[2][2] = {};
  const short* wpb = wp_b + (cs * 32) * 256;
  #pragma unroll 2
  for (int kk = 0; kk < 8; ++kk) {
    bf16x8 of[2], wf2[2];
    #pragma unroll
    for (int qt = 0; qt < 2; ++qt) {
      int q = qh * 32 + qt * 16 + lr;
      of[qt] = *(const bf16x8*)(&Ol[q * 256 + (((kk * 4 + lg) ^ (q & 7)) << 3)]);
    }
    #pragma unroll
    for (int mt = 0; mt < 2; ++mt)
      wf2[mt] = *(const bf16x8*)(wpb + (mt * 16 + lr) * 256 + kk * 32 + lg * 8);
    __builtin_amdgcn_s_setprio(1);
    #pragma unroll
    for (int mt = 0; mt < 2; ++mt)
      #pragma unroll
      for (int qt = 0; qt < 2; ++qt)
        po[mt][qt] = __builtin_amdgcn_mfma_f32_16x16x32_bf16(wf2[mt], of[qt], po[mt][qt], 0, 0, 0);
    __builtin_amdgcn_s_setprio(0);
  }
  float* od = out + (long)b * 49 * 256;
  #pragma unroll
  for (int mt = 0; mt < 2; ++mt) {
    int c0 = cs * 32 + mt * 16 + lg * 4;
    float4 pb = *(const float4*)(proj_b + c0);
    #pragma unroll
    for (int qt = 0; qt < 2; ++qt) {
      int q = qh * 32 + qt * 16 + lr;
      if (q < 49) {
        float4 ov;
        ov.x = po[mt][qt][0] + pb.x;
        ov.y = po[mt][qt][1] + pb.y;
        ov.z = po[mt][qt][2] + pb.z;
        ov.w = po[mt][qt][3] + pb.w;
        *(float4*)(od + q * 256 + c0) = ov;
      }
    }
  }
}

extern "C" void kernel_launch(void* const* d_in, const int* in_sizes, int n_in,
                              void* d_out, int out_size, void* d_ws, size_t ws_size,
                              hipStream_t stream) {
  const float* x      = (const float*)d_in[0];
  const float* qg     = (const float*)d_in[1];
  const float* qkv_w  = (const float*)d_in[2];
  const float* qkv_b  = (const float*)d_in[3];
  const float* proj_w = (const float*)d_in[4];
  const float* proj_b = (const float*)d_in[5];
  const float* table  = (const float*)d_in[6];
  float* out = (float*)d_out;

  char* ws = (char*)d_ws;
  short* wq_b  = (short*)ws;              // 262144 B  bf16 qkv_w [512][256]
  short* wp_b  = (short*)(ws + 262144);   // 131072 B  bf16 proj_w [256][256]
  short* q_b   = (short*)(ws + 393216);   // 2097152 B bf16 q padded [64][8][64][32]
  float* biasg = (float*)(ws + 2490368);  // 131072 B  f32 bias padded [8][64][64]
  // split-path extras:
  short* Kg  = (short*)(ws + 2621440);                // 128 MiB [4096][8][64][32]
  short* vTg = (short*)(ws + 2621440 + 134217728ULL); // 128 MiB [4096][8][2][32][32]
  const size_t NEED = 2621440ULL + 2ULL * 134217728ULL;  // ~271 MB

  const int prep_total = 131072 + 65536 + 1048576 + 32768;
  prep_kernel<<<(prep_total + 255) / 256, 256, 0, stream>>>(
      qkv_w, proj_w, qg, table, wq_b, wp_b, q_b, biasg);

  if (ws_size >= NEED) {
    kv_win<<<4096, 1024, 0, stream>>>(x, wq_b, qkv_b, Kg, vTg);
    attn_win<<<4096, 1024, 0, stream>>>(Kg, vTg, q_b, wp_b, proj_b, biasg, out);
  } else {
    fused_win<<<4096, 1024, 0, stream>>>(x, q_b, wq_b, wp_b, qkv_b, proj_b, biasg, out);
  }
}

// Round 10
// 395.556 us; speedup vs baseline: 2.3230x; 1.2596x over previous
//
#include <hip/hip_runtime.h>
#include <hip/hip_bf16.h>

typedef __attribute__((ext_vector_type(4))) float f32x4;
typedef __attribute__((ext_vector_type(8))) short bf16x8;
typedef __attribute__((ext_vector_type(4))) short s16x4;

__device__ __forceinline__ short f2bf(float f) {
  __hip_bfloat16 h = __float2bfloat16(f);     // native v_cvt (RNE), pk-fusable
  return *reinterpret_cast<short*>(&h);
}

__device__ __forceinline__ bf16x8 pack8(float4 a, float4 b) {
  bf16x8 v;
  v[0] = f2bf(a.x); v[1] = f2bf(a.y); v[2] = f2bf(a.z); v[3] = f2bf(a.w);
  v[4] = f2bf(b.x); v[5] = f2bf(b.y); v[6] = f2bf(b.z); v[7] = f2bf(b.w);
  return v;
}

// ---------------- prep: weights->bf16, q padded->bf16, bias [8][64][64] -----
__global__ __launch_bounds__(256) void prep_kernel(
    const float* __restrict__ qkv_w, const float* __restrict__ proj_w,
    const float* __restrict__ qg, const float* __restrict__ table,
    short* __restrict__ wq_b, short* __restrict__ wp_b,
    short* __restrict__ q_b, float* __restrict__ biasg)
{
  int idx = blockIdx.x * 256 + threadIdx.x;
  if (idx < 131072) { wq_b[idx] = f2bf(qkv_w[idx]); return; }
  idx -= 131072;
  if (idx < 65536) { wp_b[idx] = f2bf(proj_w[idx]); return; }
  idx -= 65536;
  if (idx < 1048576) {                       // q padded: [64 win][8 h][64 n][32 d]
    int d = idx & 31, n = (idx >> 5) & 63, hh = (idx >> 11) & 7, w = idx >> 14;
    float v = (n < 49) ? qg[((w * 8 + hh) * 49 + n) * 32 + d] : 0.f;
    q_b[idx] = f2bf(v);
    return;
  }
  idx -= 1048576;
  if (idx < 32768) {                         // bias padded: [8 h][64 q][64 k]
    int hh = idx >> 12, rem = idx & 4095;
    int q = rem >> 6, k = rem & 63;
    float v = 0.f;
    if (q < 49 && k < 49) {
      int di = q / 7 - k / 7 + 6, dj = q % 7 - k % 7 + 6;
      v = table[(di * 13 + dj) * 8 + hh];
    }
    biasg[idx] = v;
  }
}

// ---------------- fused per-window kernel (r4 structure, padded-stride LDS) -
// block = 1 window, 1024 thr = 16 waves. LDS row strides are ~4 banks mod 32
// (NOT a multiple of 128B): rows rotate across banks, b128 alignment kept,
// zero swizzle math.  ROUND-9 BUG FIXED: As stride must cover 256 cols (264),
// not the r4 half-tile stride 136 (overran rows + region -> corrupted x).
//   As/Ol [64][264] 33792 B @0       (x tile; aliased by attn-out after B2)
//   Kl    [64][264] 33792 B @33792   (K, row=key, col=c)
//   vT    [256][72] 36864 B @67584   (V^T, row=d, col=key)
//   Pw 16x[32][40]  40960 B @104448  (per-wave P bounce, dedicated)
// total 145408 B. 1 block/CU (reg-pinned anyway) -> 3 barriers.
__global__ __launch_bounds__(1024, 4) void fused_win(
    const float* __restrict__ x, const short* __restrict__ q_b,
    const short* __restrict__ wq_b, const short* __restrict__ wp_b,
    const float* __restrict__ qkv_b, const float* __restrict__ proj_b,
    const float* __restrict__ biasg, float* __restrict__ out)
{
  __shared__ __align__(16) char smem[145408];
  short* As = (short*)smem;                       // stride 264
  short* Kl = (short*)(smem + 33792);             // stride 264
  short* vT = (short*)(smem + 67584);             // stride 72
  short* Ol = (short*)smem;                       // stride 264, aliases As

  const int tid = threadIdx.x;
  const int b   = blockIdx.x;
  const int lane = tid & 63;
  const int w   = tid >> 6;        // 0..15
  const int lr  = lane & 15;
  const int lg  = lane >> 4;
  short* Pw = (short*)(smem + 104448 + w * 2560); // [32][40]

  // -- phase 0: stage full x tile f32->bf16, rows 49..63 zero ---------------
  const float* xsrc = x + (long)b * 49 * 256;
  #pragma unroll
  for (int it = 0; it < 2; ++it) {
    int slot = it * 1024 + tid;                   // 2048 slots = 64 rows x 32
    int row = slot >> 5, s = slot & 31;
    bf16x8 v = {};
    if (row < 49) {
      const float4* p = (const float4*)(xsrc + row * 256 + s * 8);
      v = pack8(p[0], p[1]);
    }
    *(bf16x8*)(&As[row * 264 + s * 8]) = v;
  }
  __syncthreads();                                // B1 (x staged)

  // -- phase 1: kv = x @ qkv_w^T ---------------------------------------------
  // waves 0-7 (K, swapped): acc rows=c(32), cols=key(64)
  // waves 8-15 (V, normal): acc rows=key(64), cols=d(32)
  const bool isK = (w < 8);
  f32x4 acc[8] = {};
  const short* wbase = wq_b + ((isK ? 0 : 256) + (w & 7) * 32) * 256;

  #pragma unroll
  for (int kk = 0; kk < 8; ++kk) {
    bf16x8 xa[4], wf[2];
    #pragma unroll
    for (int t = 0; t < 4; ++t)
      xa[t] = *(const bf16x8*)(&As[(t * 16 + lr) * 264 + (kk * 4 + lg) * 8]);
    #pragma unroll
    for (int t = 0; t < 2; ++t)
      wf[t] = *(const bf16x8*)(wbase + (t * 16 + lr) * 256 + kk * 32 + lg * 8);
    __builtin_amdgcn_s_setprio(1);
    if (isK) {
      #pragma unroll
      for (int mt = 0; mt < 2; ++mt)
        #pragma unroll
        for (int nt = 0; nt < 4; ++nt)
          acc[mt * 4 + nt] = __builtin_amdgcn_mfma_f32_16x16x32_bf16(wf[mt], xa[nt], acc[mt * 4 + nt], 0, 0, 0);
    } else {
      #pragma unroll
      for (int mt = 0; mt < 4; ++mt)
        #pragma unroll
        for (int nt = 0; nt < 2; ++nt)
          acc[mt * 2 + nt] = __builtin_amdgcn_mfma_f32_16x16x32_bf16(xa[mt], wf[nt], acc[mt * 2 + nt], 0, 0, 0);
    }
    __builtin_amdgcn_s_setprio(0);
  }

  // epilogue: +qkv_b, b64 LDS writes (padded strides)
  if (isK) {         // lane: c = w*32+mt*16+lg*4 (+r), key = nt*16+lr
    #pragma unroll
    for (int mt = 0; mt < 2; ++mt) {
      int c0 = w * 32 + mt * 16 + lg * 4;
      float4 bv = *(const float4*)(qkv_b + c0);
      #pragma unroll
      for (int nt = 0; nt < 4; ++nt) {
        int key = nt * 16 + lr;
        s16x4 sv;
        sv[0] = f2bf(acc[mt * 4 + nt][0] + bv.x);
        sv[1] = f2bf(acc[mt * 4 + nt][1] + bv.y);
        sv[2] = f2bf(acc[mt * 4 + nt][2] + bv.z);
        sv[3] = f2bf(acc[mt * 4 + nt][3] + bv.w);
        *(s16x4*)(&Kl[key * 264 + c0]) = sv;
      }
    }
  } else {           // lane: key = mt*16+lg*4 (+r), d = (w-8)*32+nt*16+lr
    #pragma unroll
    for (int nt = 0; nt < 2; ++nt) {
      int d = (w - 8) * 32 + nt * 16 + lr;
      float bv = qkv_b[256 + d];
      #pragma unroll
      for (int mt = 0; mt < 4; ++mt) {
        int key0 = mt * 16 + lg * 4;
        s16x4 sv;
        sv[0] = f2bf(acc[mt * 2 + nt][0] + bv);
        sv[1] = f2bf(acc[mt * 2 + nt][1] + bv);
        sv[2] = f2bf(acc[mt * 2 + nt][2] + bv);
        sv[3] = f2bf(acc[mt * 2 + nt][3] + bv);
        *(s16x4*)(&vT[d * 72 + key0]) = sv;
      }
    }
  }
  __syncthreads();                                // B2 (K/V ready; As reads done)

  // -- phase 2: S^T = mfma(K, Q); wave = (head h, q-half qh) ----------------
  const int h = w >> 1, qh = w & 1;
  f32x4 st[4][2] = {};
  {
    const short* qsrc = q_b + ((long)(b >> 6) * 8 + h) * 2048 + qh * 1024;
    bf16x8 qa[2], kb[4];
    #pragma unroll
    for (int qt = 0; qt < 2; ++qt)
      qa[qt] = *(const bf16x8*)(qsrc + (qt * 16 + lr) * 32 + lg * 8);
    #pragma unroll
    for (int kt = 0; kt < 4; ++kt)
      kb[kt] = *(const bf16x8*)(&Kl[(kt * 16 + lr) * 264 + h * 32 + lg * 8]);
    __builtin_amdgcn_s_setprio(1);
    #pragma unroll
    for (int kt = 0; kt < 4; ++kt)
      #pragma unroll
      for (int qt = 0; qt < 2; ++qt)
        st[kt][qt] = __builtin_amdgcn_mfma_f32_16x16x32_bf16(kb[kt], qa[qt], st[kt][qt], 0, 0, 0);
    __builtin_amdgcn_s_setprio(0);
  }

  // -- phase 3: softmax; row q = qh*32+qt*16+lr, keys in-lane (2 shfls) -----
  {
    const float* bh = biasg + h * 4096;
    const float sc = 0.17677669529663687f;        // 32^-0.5
    #pragma unroll
    for (int qt = 0; qt < 2; ++qt) {
      int q = qh * 32 + qt * 16 + lr;
      float mx = -1e30f;
      #pragma unroll
      for (int kt = 0; kt < 4; ++kt) {
        int key0 = kt * 16 + lg * 4;
        float4 bv = *(const float4*)(bh + q * 64 + key0);
        #pragma unroll
        for (int r = 0; r < 4; ++r) {
          float t = st[kt][qt][r] * sc + ((r == 0) ? bv.x : (r == 1) ? bv.y : (r == 2) ? bv.z : bv.w);
          if (key0 + r >= 49) t = -1e30f;
          st[kt][qt][r] = t;
          mx = fmaxf(mx, t);
        }
      }
      mx = fmaxf(mx, __shfl_xor(mx, 16));
      mx = fmaxf(mx, __shfl_xor(mx, 32));
      float sum = 0.f;
      #pragma unroll
      for (int kt = 0; kt < 4; ++kt)
        #pragma unroll
        for (int r = 0; r < 4; ++r) {
          float e = __expf(st[kt][qt][r] - mx);
          st[kt][qt][r] = e; sum += e;
        }
      sum += __shfl_xor(sum, 16);
      sum += __shfl_xor(sum, 32);
      float rinv = 1.f / sum;                     // fold 1/sum into P
      #pragma unroll
      for (int kt = 0; kt < 4; ++kt)
        #pragma unroll
        for (int r = 0; r < 4; ++r) st[kt][qt][r] *= rinv;
    }
  }

  // -- phase 4: O^T = mfma(V^T, P^T); P via dedicated per-wave LDS ----------
  f32x4 o[2][2] = {};
  #pragma unroll
  for (int ks = 0; ks < 2; ++ks) {
    #pragma unroll
    for (int kh = 0; kh < 2; ++kh) {
      int kt = ks * 2 + kh;
      int kloc0 = kh * 16 + lg * 4;
      #pragma unroll
      for (int qt = 0; qt < 2; ++qt) {
        int qloc = qt * 16 + lr;
        s16x4 sv;
        sv[0] = f2bf(st[kt][qt][0]);
        sv[1] = f2bf(st[kt][qt][1]);
        sv[2] = f2bf(st[kt][qt][2]);
        sv[3] = f2bf(st[kt][qt][3]);
        *(s16x4*)(&Pw[qloc * 40 + kloc0]) = sv;
      }
    }
    bf16x8 pa[2], vb[2];
    #pragma unroll
    for (int qt = 0; qt < 2; ++qt)
      pa[qt] = *(const bf16x8*)(&Pw[(qt * 16 + lr) * 40 + lg * 8]);
    #pragma unroll
    for (int dt = 0; dt < 2; ++dt)
      vb[dt] = *(const bf16x8*)(&vT[(h * 32 + dt * 16 + lr) * 72 + ks * 32 + lg * 8]);
    __builtin_amdgcn_s_setprio(1);
    #pragma unroll
    for (int dt = 0; dt < 2; ++dt)
      #pragma unroll
      for (int qt = 0; qt < 2; ++qt)
        o[dt][qt] = __builtin_amdgcn_mfma_f32_16x16x32_bf16(vb[dt], pa[qt], o[dt][qt], 0, 0, 0);
    __builtin_amdgcn_s_setprio(0);
  }

  // -- phase 5: O^T -> Ol[q][c] (aliases As; all As reads ended at B2) ------
  #pragma unroll
  for (int dt = 0; dt < 2; ++dt) {
    int c0 = h * 32 + dt * 16 + lg * 4;
    #pragma unroll
    for (int qt = 0; qt < 2; ++qt) {
      int q = qh * 32 + qt * 16 + lr;
      s16x4 sv;
      sv[0] = f2bf(o[dt][qt][0]);
      sv[1] = f2bf(o[dt][qt][1]);
      sv[2] = f2bf(o[dt][qt][2]);
      sv[3] = f2bf(o[dt][qt][3]);
      *(s16x4*)(&Ol[q * 264 + c0]) = sv;
    }
  }
  __syncthreads();                                // B3 (Ol ready)

  // -- phase 6: out = O @ proj_w^T + proj_b (swapped -> float4 stores) ------
  const int cs = w >> 1;                          // 32-col strip 0..7
  f32x4 po[2][2] = {};
  const short* wpb = wp_b + (cs * 32) * 256;
  #pragma unroll 2
  for (int kk = 0; kk < 8; ++kk) {
    bf16x8 of[2], wf2[2];
    #pragma unroll
    for (int qt = 0; qt < 2; ++qt) {
      int q = qh * 32 + qt * 16 + lr;
      of[qt] = *(const bf16x8*)(&Ol[q * 264 + kk * 32 + lg * 8]);
    }
    #pragma unroll
    for (int mt = 0; mt < 2; ++mt)
      wf2[mt] = *(const bf16x8*)(wpb + (mt * 16 + lr) * 256 + kk * 32 + lg * 8);
    __builtin_amdgcn_s_setprio(1);
    #pragma unroll
    for (int mt = 0; mt < 2; ++mt)
      #pragma unroll
      for (int qt = 0; qt < 2; ++qt)
        po[mt][qt] = __builtin_amdgcn_mfma_f32_16x16x32_bf16(wf2[mt], of[qt], po[mt][qt], 0, 0, 0);
    __builtin_amdgcn_s_setprio(0);
  }
  float* od = out + (long)b * 49 * 256;
  #pragma unroll
  for (int mt = 0; mt < 2; ++mt) {
    int c0 = cs * 32 + mt * 16 + lg * 4;
    float4 pb = *(const float4*)(proj_b + c0);
    #pragma unroll
    for (int qt = 0; qt < 2; ++qt) {
      int q = qh * 32 + qt * 16 + lr;
      if (q < 49) {
        float4 ov;
        ov.x = po[mt][qt][0] + pb.x;
        ov.y = po[mt][qt][1] + pb.y;
        ov.z = po[mt][qt][2] + pb.z;
        ov.w = po[mt][qt][3] + pb.w;
        *(float4*)(od + q * 256 + c0) = ov;
      }
    }
  }
}

extern "C" void kernel_launch(void* const* d_in, const int* in_sizes, int n_in,
                              void* d_out, int out_size, void* d_ws, size_t ws_size,
                              hipStream_t stream) {
  const float* x      = (const float*)d_in[0];
  const float* qg     = (const float*)d_in[1];
  const float* qkv_w  = (const float*)d_in[2];
  const float* qkv_b  = (const float*)d_in[3];
  const float* proj_w = (const float*)d_in[4];
  const float* proj_b = (const float*)d_in[5];
  const float* table  = (const float*)d_in[6];
  float* out = (float*)d_out;

  char* ws = (char*)d_ws;                 // total scratch: ~2.62 MB
  short* wq_b  = (short*)ws;              // 262144 B  bf16 qkv_w [512][256]
  short* wp_b  = (short*)(ws + 262144);   // 131072 B  bf16 proj_w [256][256]
  short* q_b   = (short*)(ws + 393216);   // 2097152 B bf16 q padded [64][8][64][32]
  float* biasg = (float*)(ws + 2490368);  // 131072 B  f32 bias padded [8][64][64]

  const int prep_total = 131072 + 65536 + 1048576 + 32768;
  prep_kernel<<<(prep_total + 255) / 256, 256, 0, stream>>>(
      qkv_w, proj_w, qg, table, wq_b, wp_b, q_b, biasg);
  fused_win<<<4096, 1024, 0, stream>>>(x, q_b, wq_b, wp_b, qkv_b, proj_b, biasg, out);
}